// Round 10
// baseline (113.582 us; speedup 1.0000x reference)
//
#include <hip/hip_runtime.h>
#include <math.h>

constexpr int NB = 16;    // batch
constexpr int SL = 1024;  // L
constexpr int ND = 128;   // D
constexpr int NH = 256;   // H
constexpr int SPAD = 576; // padded spectrum/time length (9*64)

// bf16 plane layout in ws (ushort element indices)
constexpr size_t PLANE  = (size_t)NB * ND * SPAD;
constexpr size_t CS_OFF = 0;            // cs  [b][d][s]
constexpr size_t DD_OFF = PLANE;        // dd  [b][d][s]
constexpr size_t FR_OFF = 2 * PLANE;    // Frw [b][d][k]  (weighted, includes 1/l)
constexpr size_t FI_OFF = 3 * PLANE;    // Fiw [b][d][k]
// float scratch after the 4 bf16 planes (float element indices)
constexpr size_t F32B      = 2 * PLANE;
constexpr size_t P_OFF     = F32B;                  // [2][16][16][128]
constexpr size_t SCALE_OFF = P_OFF + 2 * 16 * 16 * 128;
constexpr size_t BIAS_OFF  = SCALE_OFF + NB * ND;

constexpr float TWO_PI = 6.283185307179586f;

typedef float          f32x4 __attribute__((ext_vector_type(4)));
typedef unsigned int   u32x4 __attribute__((ext_vector_type(4)));
typedef unsigned short u16x8 __attribute__((ext_vector_type(8)));

__device__ __forceinline__ unsigned short f2bf(float f) {
    unsigned u = __float_as_uint(f);
    return (unsigned short)((u + 0x7FFFu + ((u >> 16) & 1u)) >> 16);
}
__device__ __forceinline__ void mfma16(f32x4& acc, u32x4 a, u32x4 b) {
    asm("v_mfma_f32_16x16x32_bf16 %0, %1, %2, %0" : "+v"(acc) : "v"(a), "v"(b));
}

// ---------------- K1: partial sums of y and z over t ----------------
__global__ __launch_bounds__(256) void k_partial(const float* __restrict__ y,
                                                 const float* __restrict__ z,
                                                 float* __restrict__ ws) {
    const int blk = blockIdx.x;          // 512 = src*256 + b*16 + ch
    const int ch  = blk & 15;
    const int b   = (blk >> 4) & 15;
    const int src = blk >> 8;
    const float* base = (src == 0 ? y : z) + (size_t)b * SL * ND;
    const int d    = threadIdx.x & 127;
    const int half = threadIdx.x >> 7;
    float s = 0.f;
    const int t0 = ch * 64 + half;
    for (int j = 0; j < 32; ++j)
        s += base[(size_t)(t0 + 2 * j) * ND + d];
    __shared__ float red[256];
    red[threadIdx.x] = s;
    __syncthreads();
    if (half == 0)
        ws[P_OFF + ((size_t)((src * NB + b) * 16 + ch)) * ND + d] = s + red[d + 128];
}

// ---------------- K2: MLPs -> scale/bias ----------------
__global__ __launch_bounds__(256) void k_mlp(
    float* __restrict__ ws,
    const int* __restrict__ len_y, const int* __restrict__ len_z,
    const float* __restrict__ W1w1, const float* __restrict__ W1b1,
    const float* __restrict__ W1w2, const float* __restrict__ W1b2,
    const float* __restrict__ B1w1, const float* __restrict__ B1b1,
    const float* __restrict__ B1w2, const float* __restrict__ B1b2,
    const float* __restrict__ W2w1, const float* __restrict__ W2b1,
    const float* __restrict__ W2w2, const float* __restrict__ W2b2,
    const float* __restrict__ B2w1, const float* __restrict__ B2b1,
    const float* __restrict__ B2w2, const float* __restrict__ B2b2) {
    const int b = blockIdx.x;
    const int tid = threadIdx.x;
    __shared__ float c1[ND], c2[ND];
    __shared__ float h[4][NH];
    __shared__ float o[4][ND];

    if (tid < ND) {
        float s = 0.f;
        for (int ch = 0; ch < 16; ++ch)
            s += ws[P_OFF + ((size_t)((0 * NB + b) * 16 + ch)) * ND + tid];
        c1[tid] = s / (float)len_y[b];
    } else {
        const int d = tid - ND;
        float s = 0.f;
        for (int ch = 0; ch < 16; ++ch)
            s += ws[P_OFF + ((size_t)((1 * NB + b) * 16 + ch)) * ND + d];
        c2[d] = s / (float)len_z[b];
    }
    __syncthreads();

    const float* w1s[4] = {W1w1, B1w1, W2w1, B2w1};
    const float* b1s[4] = {W1b1, B1b1, W2b1, B2b1};
    const float* w2s[4] = {W1w2, B1w2, W2w2, B2w2};
    const float* b2s[4] = {W1b2, B1b2, W2b2, B2b2};

    for (int m = 0; m < 4; ++m) {
        const float* c = (m < 2) ? c1 : c2;
        const float* w = w1s[m];
        const int j = tid;
        float s = b1s[m][j];
        for (int i = 0; i < ND; ++i)
            s = fmaf(c[i], w[i * NH + j], s);
        h[m][j] = 0.5f * s * (1.f + erff(s * 0.7071067811865475f));
    }
    __syncthreads();

    for (int p = tid; p < 4 * ND; p += 256) {
        const int m = p >> 7, d = p & 127;
        const float* w = w2s[m];
        float s = b2s[m][d];
        for (int j = 0; j < NH; ++j)
            s = fmaf(h[m][j], w[j * ND + d], s);
        o[m][d] = s;
    }
    __syncthreads();

    if (tid < ND) {
        ws[SCALE_OFF + b * ND + tid] = 1.f + 0.5f * (o[0][tid] + o[2][tid]);
        ws[BIAS_OFF  + b * ND + tid] = 0.5f * (o[1][tid] + o[3][tid]);
    }
}

// ---------------- K3: fold x -> cs/dd bf16 planes [b][d][s] + FR/FI tail zero ----
// grid (18, NB), 256 thr.
__global__ __launch_bounds__(256) void k_prep(const float* __restrict__ x,
                                              const int* __restrict__ len_x,
                                              unsigned short* __restrict__ wsb) {
    const int b = blockIdx.y;
    const int l = len_x[b];
    const int NS = (l >> 1) + 1;
    const int tid = threadIdx.x;
    const int d = tid & 127;
    const int slot = tid >> 7;
#pragma unroll
    for (int it = 0; it < 2; ++it) {
        const int sb = (blockIdx.x * 4 + slot * 2 + it) * 8;
        u16x8 cb, db;
#pragma unroll
        for (int j = 0; j < 8; ++j) {
            const int s = sb + j;
            float c = 0.f, dd = 0.f;
            if (s < NS) {
                const float a = x[((size_t)b * SL + s) * ND + d];
                float p = 0.f;
                if (s > 0 && 2 * s != l) p = x[((size_t)b * SL + (l - s)) * ND + d];
                c = a + p; dd = a - p;
            }
            cb[j] = f2bf(c); db[j] = f2bf(dd);
        }
        const size_t ro = ((size_t)b * ND + d) * SPAD + sb;
        *(u16x8*)&wsb[CS_OFF + ro] = cb;
        *(u16x8*)&wsb[DD_OFF + ro] = db;
        if (sb + 7 >= NS) {   // zero FR/FI tail rows (k_fwd later writes rows < NS)
            const u16x8 zz = {0, 0, 0, 0, 0, 0, 0, 0};
            *(u16x8*)&wsb[FR_OFF + ro] = zz;
            *(u16x8*)&wsb[FI_OFF + ro] = zz;
        }
    }
}

// ---------------- K4: forward DFT via MFMA + filter -> Frw/Fiw planes ----------------
// grid (33 ktiles, NB), 512 thr = 8 waves; wave w handles d-group [16w, 16w+16).
// Fixed 9 chunks of 64 s-slots over zero-padded planes.
__global__ __launch_bounds__(512) void k_fwd(const int* __restrict__ len_x,
                                             const float* __restrict__ wsf,
                                             unsigned short* __restrict__ wsb) {
    const int b = blockIdx.y;
    const int l = len_x[b];
    const int NS = (l >> 1) + 1;
    const int kbase = blockIdx.x * 16;
    if (kbase >= NS) return;
    const float invl = 1.f / (float)l;
    const float fl = (float)l;

    __shared__ __align__(16) unsigned short Ec[16][72];
    __shared__ __align__(16) unsigned short Es[16][72];

    const int tid = threadIdx.x;
    const int lane = tid & 63, wave = tid >> 6;
    const int dbase = wave * 16;
    const int lrow = lane & 15, lkg = lane >> 4;

    // E-gen mapping: row = tid>>5 (0..15), spair = (tid&31)*2
    const int grow = tid >> 5;
    const int spair = (tid & 31) * 2;
    const int kmine = kbase + grow;
    float stre, stim;  // e^{-2pi i k/l}
    sincosf(-TWO_PI * (float)kmine * invl, &stim, &stre);

    f32x4 accR = 0.f, accI = 0.f;

    for (int s0 = 0; s0 < SPAD; s0 += 64) {
        __syncthreads();
        {
            const int sg = s0 + spair;
            float cre, cim;
            const float ks = (float)kmine * (float)sg;   // exact (<2^24)
            float idxf = fmaf(-fl, floorf(ks * invl), ks);
            idxf = (idxf < 0.f) ? idxf + fl : idxf;
            idxf = (idxf >= fl) ? idxf - fl : idxf;
            sincosf(-TWO_PI * idxf * invl, &cim, &cre);
            const unsigned short c0 = (sg < NS) ? f2bf(cre) : (unsigned short)0;
            const unsigned short s0b = (sg < NS) ? f2bf(cim) : (unsigned short)0;
            const float ncr = fmaf(cre, stre, -cim * stim);
            const float nci = fmaf(cre, stim, cim * stre);
            const unsigned short c1 = (sg + 1 < NS) ? f2bf(ncr) : (unsigned short)0;
            const unsigned short s1b = (sg + 1 < NS) ? f2bf(nci) : (unsigned short)0;
            *(unsigned int*)&Ec[grow][spair] = (unsigned)c0 | ((unsigned)c1 << 16);
            *(unsigned int*)&Es[grow][spair] = (unsigned)s0b | ((unsigned)s1b << 16);
        }
        __syncthreads();

#pragma unroll
        for (int sub = 0; sub < 2; ++sub) {
            const u32x4 eC = *(const u32x4*)&Ec[lrow][sub * 32 + lkg * 8];
            const u32x4 eS = *(const u32x4*)&Es[lrow][sub * 32 + lkg * 8];
            const int drow = dbase + lrow;
            const size_t ro = ((size_t)b * ND + drow) * SPAD + s0 + sub * 32 + lkg * 8;
            const u32x4 aC = *(const u32x4*)&wsb[CS_OFF + ro];
            const u32x4 aD = *(const u32x4*)&wsb[DD_OFF + ro];
            mfma16(accR, aC, eC);
            mfma16(accI, aD, eS);
        }
    }

    const int kcol = kbase + lrow;
    if (kcol >= NS) return;
    const float w = ((kcol == 0 || 2 * kcol == l) ? 1.f : 2.f) * invl;
#pragma unroll
    for (int r = 0; r < 4; ++r) {
        const int drow = dbase + lkg * 4 + r;
        const float sc = wsf[SCALE_OFF + b * ND + drow];
        const float bi = wsf[BIAS_OFF + b * ND + drow];
        const size_t o = ((size_t)b * ND + drow) * SPAD + kcol;
        wsb[FR_OFF + o] = f2bf(w * fmaf(accR[r], sc, bi));
        wsb[FI_OFF + o] = f2bf(w * accI[r] * sc);
    }
}

// ---------------- K5: inverse DFT via MFMA, t-folded real output + tail zeroing ----
// grid (64 ttiles, NB), 512 thr = 8 waves; wave w handles d-group [16w, 16w+16).
__global__ __launch_bounds__(512) void k_inv(const int* __restrict__ len_x,
                                             const unsigned short* __restrict__ wsb,
                                             float* __restrict__ out) {
    const int b = blockIdx.y;
    const int l = len_x[b];
    const int NS = (l >> 1) + 1;
    const int tbase = blockIdx.x * 16;
    const int tid = threadIdx.x;

    if (tbase >= NS) {
        const int row = tbase + (tid >> 5);
        if (row >= l && row < SL) {
            const int c4 = (tid & 31) * 4;
            float4 zz = make_float4(0.f, 0.f, 0.f, 0.f);
            *(float4*)&out[((size_t)b * SL + row) * ND + c4] = zz;
        }
        return;
    }

    const float invl = 1.f / (float)l;
    const float fl = (float)l;

    __shared__ __align__(16) unsigned short E2c[16][72];
    __shared__ __align__(16) unsigned short E2s[16][72];

    const int lane = tid & 63, wave = tid >> 6;
    const int dbase = wave * 16;
    const int lrow = lane & 15, lkg = lane >> 4;

    const int grow = tid >> 5;
    const int kpair = (tid & 31) * 2;
    const int tmine = tbase + grow;
    float stre, stim;  // e^{+2pi i t/l}
    sincosf(TWO_PI * (float)tmine * invl, &stim, &stre);

    f32x4 accA = 0.f, accB = 0.f;

    for (int k0 = 0; k0 < SPAD; k0 += 64) {
        __syncthreads();
        {
            const int kg = k0 + kpair;
            float cre, cim;
            const float tk = (float)tmine * (float)kg;
            float idxf = fmaf(-fl, floorf(tk * invl), tk);
            idxf = (idxf < 0.f) ? idxf + fl : idxf;
            idxf = (idxf >= fl) ? idxf - fl : idxf;
            sincosf(TWO_PI * idxf * invl, &cim, &cre);
            const unsigned short c0 = f2bf(cre);
            const unsigned short s0b = f2bf(cim);
            const float ncr = fmaf(cre, stre, -cim * stim);
            const float nci = fmaf(cre, stim, cim * stre);
            const unsigned short c1 = f2bf(ncr);
            const unsigned short s1b = f2bf(nci);
            *(unsigned int*)&E2c[grow][kpair] = (unsigned)c0 | ((unsigned)c1 << 16);
            *(unsigned int*)&E2s[grow][kpair] = (unsigned)s0b | ((unsigned)s1b << 16);
        }
        __syncthreads();

#pragma unroll
        for (int sub = 0; sub < 2; ++sub) {
            const u32x4 aC = *(const u32x4*)&E2c[lrow][sub * 32 + lkg * 8];
            const u32x4 aS = *(const u32x4*)&E2s[lrow][sub * 32 + lkg * 8];
            const int dcol = dbase + lrow;
            const size_t ro = ((size_t)b * ND + dcol) * SPAD + k0 + sub * 32 + lkg * 8;
            const u32x4 bR = *(const u32x4*)&wsb[FR_OFF + ro];
            const u32x4 bI = *(const u32x4*)&wsb[FI_OFF + ro];
            mfma16(accA, aC, bR);
            mfma16(accB, aS, bI);
        }
    }

#pragma unroll
    for (int r = 0; r < 4; ++r) {
        const int trow = tbase + lkg * 4 + r;
        if (trow >= NS) continue;
        const int dcol = dbase + lrow;
        const float vA = accA[r], vB = accB[r];
        out[((size_t)b * SL + trow) * ND + dcol] = vA - vB;
        if (trow > 0 && 2 * trow != l)
            out[((size_t)b * SL + (l - trow)) * ND + dcol] = vA + vB;
    }
}

extern "C" void kernel_launch(void* const* d_in, const int* in_sizes, int n_in,
                              void* d_out, int out_size, void* d_ws, size_t ws_size,
                              hipStream_t stream) {
    const float* x = (const float*)d_in[0];
    const float* y = (const float*)d_in[1];
    const float* z = (const float*)d_in[2];
    const int* len_x = (const int*)d_in[3];
    const int* len_y = (const int*)d_in[4];
    const int* len_z = (const int*)d_in[5];
    float* wsf = (float*)d_ws;
    unsigned short* wsb = (unsigned short*)d_ws;
    float* out = (float*)d_out;

    k_partial<<<512, 256, 0, stream>>>(y, z, wsf);

    k_prep<<<dim3(18, NB), 256, 0, stream>>>(x, len_x, wsb);

    k_mlp<<<NB, 256, 0, stream>>>(wsf, len_y, len_z,
        (const float*)d_in[6],  (const float*)d_in[7],  (const float*)d_in[8],  (const float*)d_in[9],
        (const float*)d_in[10], (const float*)d_in[11], (const float*)d_in[12], (const float*)d_in[13],
        (const float*)d_in[14], (const float*)d_in[15], (const float*)d_in[16], (const float*)d_in[17],
        (const float*)d_in[18], (const float*)d_in[19], (const float*)d_in[20], (const float*)d_in[21]);

    k_fwd<<<dim3(33, NB), 512, 0, stream>>>(len_x, wsf, wsb);

    k_inv<<<dim3(64, NB), 512, 0, stream>>>(len_x, wsb, out);
}

// Round 11
// 97.611 us; speedup vs baseline: 1.1636x; 1.1636x over previous
//
#include <hip/hip_runtime.h>
#include <math.h>

constexpr int NB = 16;    // batch
constexpr int SL = 1024;  // L
constexpr int ND = 128;   // D
constexpr int NH = 256;   // H
constexpr int SPAD = 576; // padded spectrum/time length (18*32)

// bf16 plane layout in ws (ushort element indices)
constexpr size_t PLANE  = (size_t)NB * ND * SPAD;
constexpr size_t CS_OFF = 0;            // cs  [b][d][s]
constexpr size_t DD_OFF = PLANE;        // dd  [b][d][s]
constexpr size_t FR_OFF = 2 * PLANE;    // Frw [b][d][k]  (weighted, includes 1/l)
constexpr size_t FI_OFF = 3 * PLANE;    // Fiw [b][d][k]
// float scratch after the 4 bf16 planes (float element indices)
constexpr size_t F32B      = 2 * PLANE;
constexpr size_t P_OFF     = F32B;                  // [2][16][16][128]
constexpr size_t SCALE_OFF = P_OFF + 2 * 16 * 16 * 128;
constexpr size_t BIAS_OFF  = SCALE_OFF + NB * ND;
constexpr size_t H_OFF     = BIAS_OFF + NB * ND;    // [b][4][NH]

constexpr float TWO_PI = 6.283185307179586f;

typedef float          f32x4 __attribute__((ext_vector_type(4)));
typedef unsigned int   u32x4 __attribute__((ext_vector_type(4)));
typedef unsigned short u16x8 __attribute__((ext_vector_type(8)));

__device__ __forceinline__ unsigned short f2bf(float f) {
    unsigned u = __float_as_uint(f);
    return (unsigned short)((u + 0x7FFFu + ((u >> 16) & 1u)) >> 16);
}
__device__ __forceinline__ unsigned cvtpk(float lo, float hi) {
    unsigned r;
    asm("v_cvt_pk_bf16_f32 %0, %1, %2" : "=v"(r) : "v"(lo), "v"(hi));
    return r;
}
__device__ __forceinline__ void mfma16(f32x4& acc, u32x4 a, u32x4 b) {
    asm("v_mfma_f32_16x16x32_bf16 %0, %1, %2, %0" : "+v"(acc) : "v"(a), "v"(b));
}
__device__ __forceinline__ float fmodl(float p, float fl, float invl) {
    float m = fmaf(-fl, floorf(p * invl), p);
    m = (m < 0.f) ? m + fl : m;
    m = (m >= fl) ? m - fl : m;
    return m;
}

// ---------------- K1: partial sums of y and z over t ----------------
__global__ __launch_bounds__(256) void k_partial(const float* __restrict__ y,
                                                 const float* __restrict__ z,
                                                 float* __restrict__ ws) {
    const int blk = blockIdx.x;          // 512 = src*256 + b*16 + ch
    const int ch  = blk & 15;
    const int b   = (blk >> 4) & 15;
    const int src = blk >> 8;
    const float* base = (src == 0 ? y : z) + (size_t)b * SL * ND;
    const int d    = threadIdx.x & 127;
    const int half = threadIdx.x >> 7;
    float s = 0.f;
    const int t0 = ch * 64 + half;
    for (int j = 0; j < 32; ++j)
        s += base[(size_t)(t0 + 2 * j) * ND + d];
    __shared__ float red[256];
    red[threadIdx.x] = s;
    __syncthreads();
    if (half == 0)
        ws[P_OFF + ((size_t)((src * NB + b) * 16 + ch)) * ND + d] = s + red[d + 128];
}

// ---------------- K2a: MLP layer 1 + gelu -> h ----------------
__global__ __launch_bounds__(256) void k_mlp1(
    float* __restrict__ ws,
    const int* __restrict__ len_y, const int* __restrict__ len_z,
    const float* __restrict__ W1w1, const float* __restrict__ W1b1,
    const float* __restrict__ B1w1, const float* __restrict__ B1b1,
    const float* __restrict__ W2w1, const float* __restrict__ W2b1,
    const float* __restrict__ B2w1, const float* __restrict__ B2b1) {
    const int m = blockIdx.x;
    const int b = blockIdx.y;
    const int tid = threadIdx.x;
    __shared__ float c[ND];
    if (tid < ND) {
        const int src = m >> 1;
        float s = 0.f;
        for (int ch = 0; ch < 16; ++ch)
            s += ws[P_OFF + ((size_t)((src * NB + b) * 16 + ch)) * ND + tid];
        const int len = (src == 0) ? len_y[b] : len_z[b];
        c[tid] = s / (float)len;
    }
    __syncthreads();
    const float* w1s[4] = {W1w1, B1w1, W2w1, B2w1};
    const float* b1s[4] = {W1b1, B1b1, W2b1, B2b1};
    const float* w = w1s[m];
    const int j = tid;
    float s = b1s[m][j];
    for (int i = 0; i < ND; ++i)
        s = fmaf(c[i], w[i * NH + j], s);
    ws[H_OFF + ((size_t)b * 4 + m) * NH + j] = 0.5f * s * (1.f + erff(s * 0.7071067811865475f));
}

// ---------------- K2b: MLP layer 2 -> scale/bias ----------------
__global__ __launch_bounds__(256) void k_mlp2(
    float* __restrict__ ws,
    const float* __restrict__ W1w2, const float* __restrict__ W1b2,
    const float* __restrict__ B1w2, const float* __restrict__ B1b2,
    const float* __restrict__ W2w2, const float* __restrict__ W2b2,
    const float* __restrict__ B2w2, const float* __restrict__ B2b2) {
    const int b = blockIdx.x;
    const int tid = threadIdx.x;
    __shared__ float o[4][ND];
    const float* w2s[4] = {W1w2, B1w2, W2w2, B2w2};
    const float* b2s[4] = {W1b2, B1b2, W2b2, B2b2};
#pragma unroll
    for (int pp = 0; pp < 2; ++pp) {
        const int p = tid + pp * 256;
        const int m = p >> 7, d = p & 127;
        const float* hh = &ws[H_OFF + ((size_t)b * 4 + m) * NH];
        const float* w = w2s[m];
        float s = b2s[m][d];
        for (int j = 0; j < NH; ++j)
            s = fmaf(hh[j], w[j * ND + d], s);
        o[m][d] = s;
    }
    __syncthreads();
    if (tid < ND) {
        ws[SCALE_OFF + b * ND + tid] = 1.f + 0.5f * (o[0][tid] + o[2][tid]);
        ws[BIAS_OFF  + b * ND + tid] = 0.5f * (o[1][tid] + o[3][tid]);
    }
}

// ---------------- K3: fold x -> cs/dd bf16 planes [b][d][s] + FR/FI tail zero ----
// grid (18, NB), 256 thr.
__global__ __launch_bounds__(256) void k_prep(const float* __restrict__ x,
                                              const int* __restrict__ len_x,
                                              unsigned short* __restrict__ wsb) {
    const int b = blockIdx.y;
    const int l = len_x[b];
    const int NS = (l >> 1) + 1;
    const int tid = threadIdx.x;
    const int d = tid & 127;
    const int slot = tid >> 7;
#pragma unroll
    for (int it = 0; it < 2; ++it) {
        const int sb = (blockIdx.x * 4 + slot * 2 + it) * 8;
        u16x8 cb, db;
#pragma unroll
        for (int j = 0; j < 8; ++j) {
            const int s = sb + j;
            float c = 0.f, dd = 0.f;
            if (s < NS) {
                const float a = x[((size_t)b * SL + s) * ND + d];
                float p = 0.f;
                if (s > 0 && 2 * s != l) p = x[((size_t)b * SL + (l - s)) * ND + d];
                c = a + p; dd = a - p;
            }
            cb[j] = f2bf(c); db[j] = f2bf(dd);
        }
        const size_t ro = ((size_t)b * ND + d) * SPAD + sb;
        *(u16x8*)&wsb[CS_OFF + ro] = cb;
        *(u16x8*)&wsb[DD_OFF + ro] = db;
        if (sb + 7 >= NS) {   // zero FR/FI tail rows (k_fwd later writes cols < NS)
            const u16x8 zz = {0, 0, 0, 0, 0, 0, 0, 0};
            *(u16x8*)&wsb[FR_OFF + ro] = zz;
            *(u16x8*)&wsb[FI_OFF + ro] = zz;
        }
    }
}

// ---------------- K4: forward DFT via MFMA, barrier-free, in-register E-gen ----
// grid (33 ktiles, NB), 256 thr = 4 waves; wave w: d in [32w, 32w+32).
// Lane (lrow,lkg) generates E[k=kbase+lrow][s=s0+lkg*8..+7] by complex recurrence.
__global__ __launch_bounds__(256) void k_fwd(const int* __restrict__ len_x,
                                             const float* __restrict__ wsf,
                                             unsigned short* __restrict__ wsb) {
    const int b = blockIdx.y;
    const int l = len_x[b];
    const int NS = (l >> 1) + 1;
    const int kbase = blockIdx.x * 16;
    if (kbase >= NS) return;
    const float invl = 1.f / (float)l;
    const float fl = (float)l;

    const int tid = threadIdx.x;
    const int lane = tid & 63, wave = tid >> 6;
    const int dbase = wave * 32;
    const int lrow = lane & 15, lkg = lane >> 4;

    const int kmine = kbase + lrow;
    float e1r, e1i;   // e^{-2pi i k/l}
    sincosf(-TWO_PI * (float)kmine * invl, &e1i, &e1r);
    float e32r, e32i; // e^{-2pi i (32k mod l)/l}
    {
        const float mm = fmodl((float)(kmine * 32), fl, invl);
        sincosf(-TWO_PI * mm * invl, &e32i, &e32r);
    }
    float str, sti;   // state at s = lkg*8
    {
        const float mm = fmodl((float)(kmine * (lkg * 8)), fl, invl);
        sincosf(-TWO_PI * mm * invl, &sti, &str);
    }

    f32x4 accR[2], accI[2];
#pragma unroll
    for (int t = 0; t < 2; ++t) { accR[t] = 0.f; accI[t] = 0.f; }

    const size_t ro0 = ((size_t)b * ND + (dbase + lrow)) * SPAD + lkg * 8;
    const size_t ro1 = ((size_t)b * ND + (dbase + 16 + lrow)) * SPAD + lkg * 8;

    for (int s0 = 0; s0 < NS; s0 += 32) {
        // generate 8 E values: cos -> eC, (-sin accumulated sign) -> eS
        u32x4 eC, eS;
        {
            float cr = str, ci = sti;
#pragma unroll
            for (int p = 0; p < 4; ++p) {
                const float nr = fmaf(cr, e1r, -ci * e1i);
                const float ni = fmaf(cr, e1i,  ci * e1r);
                eC[p] = cvtpk(cr, nr);
                eS[p] = cvtpk(ci, ni);
                cr = fmaf(nr, e1r, -ni * e1i);
                ci = fmaf(nr, e1i,  ni * e1r);
            }
            const float tr = fmaf(str, e32r, -sti * e32i);
            const float ti = fmaf(str, e32i,  sti * e32r);
            str = tr; sti = ti;
        }
        const u32x4 aC0 = *(const u32x4*)&wsb[CS_OFF + ro0 + s0];
        const u32x4 aD0 = *(const u32x4*)&wsb[DD_OFF + ro0 + s0];
        const u32x4 aC1 = *(const u32x4*)&wsb[CS_OFF + ro1 + s0];
        const u32x4 aD1 = *(const u32x4*)&wsb[DD_OFF + ro1 + s0];
        mfma16(accR[0], aC0, eC);
        mfma16(accI[0], aD0, eS);
        mfma16(accR[1], aC1, eC);
        mfma16(accI[1], aD1, eS);
    }

    const int kcol = kbase + lrow;
    if (kcol >= NS) return;
    const float w = ((kcol == 0 || 2 * kcol == l) ? 1.f : 2.f) * invl;
#pragma unroll
    for (int t = 0; t < 2; ++t) {
#pragma unroll
        for (int r = 0; r < 4; ++r) {
            const int drow = dbase + t * 16 + lkg * 4 + r;
            const float sc = wsf[SCALE_OFF + b * ND + drow];
            const float bi = wsf[BIAS_OFF + b * ND + drow];
            const size_t o = ((size_t)b * ND + drow) * SPAD + kcol;
            wsb[FR_OFF + o] = f2bf(w * fmaf(accR[t][r], sc, bi));
            wsb[FI_OFF + o] = f2bf(w * accI[t][r] * sc);
        }
    }
}

// ---------------- K5: inverse DFT via MFMA, barrier-free, t-folded + tail zero ----
// grid (64 ttiles, NB), 256 thr = 4 waves.
// Lane (lrow,lkg) generates E2[t=tbase+lrow][k=k0+lkg*8..+7] by recurrence.
__global__ __launch_bounds__(256) void k_inv(const int* __restrict__ len_x,
                                             const unsigned short* __restrict__ wsb,
                                             float* __restrict__ out) {
    const int b = blockIdx.y;
    const int l = len_x[b];
    const int NS = (l >> 1) + 1;
    const int tbase = blockIdx.x * 16;
    const int tid = threadIdx.x;

    if (tbase >= NS) {
        const int row = tbase + (tid >> 4);
        if (row >= l && row < SL) {
            const int c = tid & 15;
            float4 zz = make_float4(0.f, 0.f, 0.f, 0.f);
            float* p = &out[((size_t)b * SL + row) * ND];
            *(float4*)&p[c * 4] = zz;
            *(float4*)&p[(c + 16) * 4] = zz;
        }
        return;
    }

    const float invl = 1.f / (float)l;
    const float fl = (float)l;

    const int lane = tid & 63, wave = tid >> 6;
    const int dbase = wave * 32;
    const int lrow = lane & 15, lkg = lane >> 4;

    const int tmine = tbase + lrow;
    float e1r, e1i;   // e^{+2pi i t/l}
    sincosf(TWO_PI * (float)tmine * invl, &e1i, &e1r);
    float e32r, e32i; // e^{+2pi i (32t mod l)/l}
    {
        const float mm = fmodl((float)(tmine * 32), fl, invl);
        sincosf(TWO_PI * mm * invl, &e32i, &e32r);
    }
    float str, sti;   // state at k = lkg*8
    {
        const float mm = fmodl((float)(tmine * (lkg * 8)), fl, invl);
        sincosf(TWO_PI * mm * invl, &sti, &str);
    }

    f32x4 accA[2], accB[2];
#pragma unroll
    for (int t = 0; t < 2; ++t) { accA[t] = 0.f; accB[t] = 0.f; }

    const size_t ro0 = ((size_t)b * ND + (dbase + lrow)) * SPAD + lkg * 8;
    const size_t ro1 = ((size_t)b * ND + (dbase + 16 + lrow)) * SPAD + lkg * 8;

    for (int k0 = 0; k0 < NS; k0 += 32) {
        u32x4 eC, eS;
        {
            float cr = str, ci = sti;
#pragma unroll
            for (int p = 0; p < 4; ++p) {
                const float nr = fmaf(cr, e1r, -ci * e1i);
                const float ni = fmaf(cr, e1i,  ci * e1r);
                eC[p] = cvtpk(cr, nr);
                eS[p] = cvtpk(ci, ni);
                cr = fmaf(nr, e1r, -ni * e1i);
                ci = fmaf(nr, e1i,  ni * e1r);
            }
            const float tr = fmaf(str, e32r, -sti * e32i);
            const float ti = fmaf(str, e32i,  sti * e32r);
            str = tr; sti = ti;
        }
        const u32x4 bR0 = *(const u32x4*)&wsb[FR_OFF + ro0 + k0];
        const u32x4 bI0 = *(const u32x4*)&wsb[FI_OFF + ro0 + k0];
        const u32x4 bR1 = *(const u32x4*)&wsb[FR_OFF + ro1 + k0];
        const u32x4 bI1 = *(const u32x4*)&wsb[FI_OFF + ro1 + k0];
        mfma16(accA[0], eC, bR0);
        mfma16(accB[0], eS, bI0);
        mfma16(accA[1], eC, bR1);
        mfma16(accB[1], eS, bI1);
    }

#pragma unroll
    for (int t = 0; t < 2; ++t) {
#pragma unroll
        for (int r = 0; r < 4; ++r) {
            const int trow = tbase + lkg * 4 + r;
            if (trow >= NS) continue;
            const int dcol = dbase + t * 16 + lrow;
            const float vA = accA[t][r], vB = accB[t][r];
            out[((size_t)b * SL + trow) * ND + dcol] = vA - vB;
            if (trow > 0 && 2 * trow != l)
                out[((size_t)b * SL + (l - trow)) * ND + dcol] = vA + vB;
        }
    }
}

extern "C" void kernel_launch(void* const* d_in, const int* in_sizes, int n_in,
                              void* d_out, int out_size, void* d_ws, size_t ws_size,
                              hipStream_t stream) {
    const float* x = (const float*)d_in[0];
    const float* y = (const float*)d_in[1];
    const float* z = (const float*)d_in[2];
    const int* len_x = (const int*)d_in[3];
    const int* len_y = (const int*)d_in[4];
    const int* len_z = (const int*)d_in[5];
    float* wsf = (float*)d_ws;
    unsigned short* wsb = (unsigned short*)d_ws;
    float* out = (float*)d_out;

    k_partial<<<512, 256, 0, stream>>>(y, z, wsf);

    k_prep<<<dim3(18, NB), 256, 0, stream>>>(x, len_x, wsb);

    k_mlp1<<<dim3(4, NB), 256, 0, stream>>>(wsf, len_y, len_z,
        (const float*)d_in[6],  (const float*)d_in[7],
        (const float*)d_in[10], (const float*)d_in[11],
        (const float*)d_in[14], (const float*)d_in[15],
        (const float*)d_in[18], (const float*)d_in[19]);

    k_mlp2<<<NB, 256, 0, stream>>>(wsf,
        (const float*)d_in[8],  (const float*)d_in[9],
        (const float*)d_in[12], (const float*)d_in[13],
        (const float*)d_in[16], (const float*)d_in[17],
        (const float*)d_in[20], (const float*)d_in[21]);

    k_fwd<<<dim3(33, NB), 256, 0, stream>>>(len_x, wsf, wsb);

    k_inv<<<dim3(64, NB), 256, 0, stream>>>(len_x, wsb, out);
}

// Round 12
// 76.482 us; speedup vs baseline: 1.4851x; 1.2763x over previous
//
#include <hip/hip_runtime.h>
#include <math.h>

constexpr int NB = 16;    // batch
constexpr int SL = 1024;  // L
constexpr int ND = 128;   // D
constexpr int NH = 256;   // H
constexpr int SPAD = 576; // padded spectrum/time length (18*32)

// bf16 plane layout in ws (ushort element indices)
constexpr size_t PLANE  = (size_t)NB * ND * SPAD;
constexpr size_t CS_OFF = 0;            // cs  [b][d][s]
constexpr size_t DD_OFF = PLANE;        // dd  [b][d][s]
constexpr size_t FR_OFF = 2 * PLANE;    // Frw [b][d][k]  (weighted, includes 1/l)
constexpr size_t FI_OFF = 3 * PLANE;    // Fiw [b][d][k]
// float scratch after the 4 bf16 planes (float element indices)
constexpr size_t F32B      = 2 * PLANE;
constexpr size_t P_OFF     = F32B;                  // [2][16][16][128]
constexpr size_t SCALE_OFF = P_OFF + 2 * 16 * 16 * 128;
constexpr size_t BIAS_OFF  = SCALE_OFF + NB * ND;

constexpr float TWO_PI = 6.283185307179586f;

typedef float          f32x4 __attribute__((ext_vector_type(4)));
typedef unsigned int   u32x4 __attribute__((ext_vector_type(4)));
typedef unsigned short u16x8 __attribute__((ext_vector_type(8)));

__device__ __forceinline__ unsigned short f2bf(float f) {
    unsigned u = __float_as_uint(f);
    return (unsigned short)((u + 0x7FFFu + ((u >> 16) & 1u)) >> 16);
}
__device__ __forceinline__ void mfma16(f32x4& acc, u32x4 a, u32x4 b) {
    asm("v_mfma_f32_16x16x32_bf16 %0, %1, %2, %0" : "+v"(acc) : "v"(a), "v"(b));
}

// ---------------- K1: fused front kernel ----------------
// blk [0,512)        : partial sums of y/z  (src*256 + b*16 + ch)
// blk [512,800)      : fold x -> cs/dd planes + FR/FI tail zero  (288 = 18*16)
// blk [800,928)      : zero out rows >= l   (128 = 16*8, rows 512..1023)
__global__ __launch_bounds__(256) void k_front(const float* __restrict__ x,
                                               const float* __restrict__ y,
                                               const float* __restrict__ z,
                                               const int* __restrict__ len_x,
                                               float* __restrict__ wsf,
                                               unsigned short* __restrict__ wsb,
                                               float* __restrict__ out) {
    const int blk = blockIdx.x;
    const int tid = threadIdx.x;

    if (blk < 512) {
        const int ch  = blk & 15;
        const int b   = (blk >> 4) & 15;
        const int src = blk >> 8;
        const float* base = (src == 0 ? y : z) + (size_t)b * SL * ND;
        const int d    = tid & 127;
        const int half = tid >> 7;
        float s = 0.f;
        const int t0 = ch * 64 + half;
        for (int j = 0; j < 32; ++j)
            s += base[(size_t)(t0 + 2 * j) * ND + d];
        __shared__ float red[256];
        red[tid] = s;
        __syncthreads();
        if (half == 0)
            wsf[P_OFF + ((size_t)((src * NB + b) * 16 + ch)) * ND + d] = s + red[d + 128];
        return;
    }

    if (blk < 800) {
        const int pb = blk - 512;
        const int bx = pb % 18;
        const int b  = pb / 18;
        const int l = len_x[b];
        const int NS = (l >> 1) + 1;
        const int d = tid & 127;
        const int slot = tid >> 7;
#pragma unroll
        for (int it = 0; it < 2; ++it) {
            const int sb = (bx * 4 + slot * 2 + it) * 8;
            u16x8 cb, db;
#pragma unroll
            for (int j = 0; j < 8; ++j) {
                const int s = sb + j;
                float c = 0.f, dd = 0.f;
                if (s < NS) {
                    const float a = x[((size_t)b * SL + s) * ND + d];
                    float p = 0.f;
                    if (s > 0 && 2 * s != l) p = x[((size_t)b * SL + (l - s)) * ND + d];
                    c = a + p; dd = a - p;
                }
                cb[j] = f2bf(c); db[j] = f2bf(dd);
            }
            const size_t ro = ((size_t)b * ND + d) * SPAD + sb;
            *(u16x8*)&wsb[CS_OFF + ro] = cb;
            *(u16x8*)&wsb[DD_OFF + ro] = db;
            if (sb + 7 >= NS) {   // zero FR/FI tail rows (k_fwd later writes cols < NS)
                const u16x8 zz = {0, 0, 0, 0, 0, 0, 0, 0};
                *(u16x8*)&wsb[FR_OFF + ro] = zz;
                *(u16x8*)&wsb[FI_OFF + ro] = zz;
            }
        }
        return;
    }

    {
        const int zb = blk - 800;
        const int b = zb >> 3;
        const int seg = zb & 7;
        const int l = len_x[b];
        // rows [512 + seg*64, 512 + seg*64 + 64): zero rows >= l
        const int row = 512 + seg * 64 + (tid >> 2);
        if (row >= l) {
            const int c16 = (tid & 3) * 32;   // 32 floats = 8 float4 per thread
            float* p = &out[((size_t)b * SL + row) * ND + c16];
            const float4 zz = make_float4(0.f, 0.f, 0.f, 0.f);
#pragma unroll
            for (int q = 0; q < 8; ++q)
                *(float4*)&p[q * 4] = zz;
        }
        return;
    }
}

// ---------------- K2: MLPs -> scale/bias (one kernel, 32 blocks) ----------------
// block = (pair, b): pair 0: {W1(c1), W2(c2)} -> scale; pair 1: {B1(c1), B2(c2)} -> bias
__global__ __launch_bounds__(256) void k_mlp(
    float* __restrict__ ws,
    const int* __restrict__ len_y, const int* __restrict__ len_z,
    const float* __restrict__ W1w1, const float* __restrict__ W1b1,
    const float* __restrict__ W1w2, const float* __restrict__ W1b2,
    const float* __restrict__ B1w1, const float* __restrict__ B1b1,
    const float* __restrict__ B1w2, const float* __restrict__ B1b2,
    const float* __restrict__ W2w1, const float* __restrict__ W2b1,
    const float* __restrict__ W2w2, const float* __restrict__ W2b2,
    const float* __restrict__ B2w1, const float* __restrict__ B2b1,
    const float* __restrict__ B2w2, const float* __restrict__ B2b2) {
    const int pair = blockIdx.x & 1;
    const int b    = blockIdx.x >> 1;
    const int tid = threadIdx.x;

    const float* w1a = pair ? B1w1 : W1w1;  const float* b1a = pair ? B1b1 : W1b1;
    const float* w2a = pair ? B1w2 : W1w2;  const float* b2a = pair ? B1b2 : W1b2;
    const float* w1b = pair ? B2w1 : W2w1;  const float* b1b = pair ? B2b1 : W2b1;
    const float* w2b = pair ? B2w2 : W2w2;  const float* b2b = pair ? B2b2 : W2b2;

    __shared__ float c1s[ND], c2s[ND];
    __shared__ float h0[NH], h1[NH];
    __shared__ float oa[ND], ob[ND];

    if (tid < ND) {
        float s = 0.f;
        for (int ch = 0; ch < 16; ++ch)
            s += ws[P_OFF + ((size_t)((0 * NB + b) * 16 + ch)) * ND + tid];
        c1s[tid] = s / (float)len_y[b];
    } else {
        const int d = tid - ND;
        float s = 0.f;
        for (int ch = 0; ch < 16; ++ch)
            s += ws[P_OFF + ((size_t)((1 * NB + b) * 16 + ch)) * ND + d];
        c2s[d] = s / (float)len_z[b];
    }
    __syncthreads();

    // layer 1 (both MLPs of the pair), j = tid
    {
        const int j = tid;
        float s0 = b1a[j], s1 = b1b[j];
        for (int i = 0; i < ND; ++i) {
            s0 = fmaf(c1s[i], w1a[i * NH + j], s0);
            s1 = fmaf(c2s[i], w1b[i * NH + j], s1);
        }
        h0[j] = 0.5f * s0 * (1.f + erff(s0 * 0.7071067811865475f));
        h1[j] = 0.5f * s1 * (1.f + erff(s1 * 0.7071067811865475f));
    }
    __syncthreads();

    // layer 2: tid<128 -> oa[tid] (K=256 over h0); tid>=128 -> ob[tid-128]
    {
        const bool second = tid >= ND;
        const int d = second ? tid - ND : tid;
        const float* w = second ? w2b : w2a;
        const float* hh = second ? h1 : h0;
        float s = second ? b2b[d] : b2a[d];
        for (int j = 0; j < NH; ++j)
            s = fmaf(hh[j], w[j * ND + d], s);
        if (second) ob[d] = s; else oa[d] = s;
    }
    __syncthreads();

    if (tid < ND) {
        if (pair == 0)
            ws[SCALE_OFF + b * ND + tid] = 1.f + 0.5f * (oa[tid] + ob[tid]);
        else
            ws[BIAS_OFF  + b * ND + tid] = 0.5f * (oa[tid] + ob[tid]);
    }
}

// ---------------- K3: forward DFT via MFMA + filter -> Frw/Fiw planes ----------------
// grid (33 ktiles, NB), 256 thr = 4 waves; wave w: d in [32w, 32w+32).
__global__ __launch_bounds__(256) void k_fwd(const int* __restrict__ len_x,
                                             const float* __restrict__ wsf,
                                             unsigned short* __restrict__ wsb) {
    const int b = blockIdx.y;
    const int l = len_x[b];
    const int NS = (l >> 1) + 1;
    const int kbase = blockIdx.x * 16;
    if (kbase >= NS) return;
    const float invl = 1.f / (float)l;
    const float fl = (float)l;

    __shared__ __align__(16) unsigned short Ec[16][40];
    __shared__ __align__(16) unsigned short Es[16][40];

    const int tid = threadIdx.x;
    const int lane = tid & 63, wave = tid >> 6;
    const int dbase = wave * 32;
    const int lrow = lane & 15, lkg = lane >> 4;

    f32x4 accR[2], accI[2];
#pragma unroll
    for (int t = 0; t < 2; ++t) { accR[t] = 0.f; accI[t] = 0.f; }

    for (int s0 = 0; s0 < NS; s0 += 32) {
        __syncthreads();
#pragma unroll
        for (int pp = 0; pp < 2; ++pp) {
            const int p = tid + pp * 256;
            const int kk = p >> 5, ss = p & 31;
            const int sg = s0 + ss;
            float cv = 0.f, sv = 0.f;
            if (sg < NS) {
                const float ks = (float)((kbase + kk) * sg);
                const float q = floorf(ks * invl);
                float idxf = fmaf(-fl, q, ks);
                idxf = (idxf < 0.f) ? idxf + fl : idxf;
                float s_, c_;
                sincosf(-TWO_PI * idxf * invl, &s_, &c_);
                cv = c_; sv = s_;
            }
            Ec[kk][ss] = f2bf(cv);
            Es[kk][ss] = f2bf(sv);
        }
        __syncthreads();

        const u32x4 eC = *(const u32x4*)&Ec[lrow][lkg * 8];
        const u32x4 eS = *(const u32x4*)&Es[lrow][lkg * 8];
#pragma unroll
        for (int t = 0; t < 2; ++t) {
            const int drow = dbase + t * 16 + lrow;
            const size_t ro = ((size_t)b * ND + drow) * SPAD + s0 + lkg * 8;
            const u32x4 aC = *(const u32x4*)&wsb[CS_OFF + ro];
            const u32x4 aD = *(const u32x4*)&wsb[DD_OFF + ro];
            mfma16(accR[t], aC, eC);
            mfma16(accI[t], aD, eS);
        }
    }

    const int kcol = kbase + lrow;
    if (kcol >= NS) return;
    const float w = ((kcol == 0 || 2 * kcol == l) ? 1.f : 2.f) * invl;
#pragma unroll
    for (int t = 0; t < 2; ++t) {
#pragma unroll
        for (int r = 0; r < 4; ++r) {
            const int drow = dbase + t * 16 + lkg * 4 + r;
            const float sc = wsf[SCALE_OFF + b * ND + drow];
            const float bi = wsf[BIAS_OFF + b * ND + drow];
            const size_t o = ((size_t)b * ND + drow) * SPAD + kcol;
            wsb[FR_OFF + o] = f2bf(w * fmaf(accR[t][r], sc, bi));
            wsb[FI_OFF + o] = f2bf(w * accI[t][r] * sc);
        }
    }
}

// ---------------- K4: inverse DFT via MFMA, t-folded real output ----------------
// grid (33 ttiles, NB), 256 thr = 4 waves. (rows >= l zeroed by k_front)
__global__ __launch_bounds__(256) void k_inv(const int* __restrict__ len_x,
                                             const unsigned short* __restrict__ wsb,
                                             float* __restrict__ out) {
    const int b = blockIdx.y;
    const int l = len_x[b];
    const int NS = (l >> 1) + 1;
    const int tbase = blockIdx.x * 16;
    if (tbase >= NS) return;
    const int tid = threadIdx.x;

    const float invl = 1.f / (float)l;
    const float fl = (float)l;

    __shared__ __align__(16) unsigned short E2c[16][40];
    __shared__ __align__(16) unsigned short E2s[16][40];

    const int lane = tid & 63, wave = tid >> 6;
    const int dbase = wave * 32;
    const int lrow = lane & 15, lkg = lane >> 4;

    f32x4 accA[2], accB[2];
#pragma unroll
    for (int t = 0; t < 2; ++t) { accA[t] = 0.f; accB[t] = 0.f; }

    for (int k0 = 0; k0 < NS; k0 += 32) {
        __syncthreads();
#pragma unroll
        for (int pp = 0; pp < 2; ++pp) {
            const int p = tid + pp * 256;
            const int tt = p >> 5, kk = p & 31;
            const int kg = k0 + kk;
            float cv = 0.f, sv = 0.f;
            if (kg < NS) {
                const float tk = (float)((tbase + tt) * kg);
                const float q = floorf(tk * invl);
                float idxf = fmaf(-fl, q, tk);
                idxf = (idxf < 0.f) ? idxf + fl : idxf;
                float s_, c_;
                sincosf(TWO_PI * idxf * invl, &s_, &c_);
                cv = c_; sv = s_;
            }
            E2c[tt][kk] = f2bf(cv);
            E2s[tt][kk] = f2bf(sv);
        }
        __syncthreads();

        const u32x4 aC = *(const u32x4*)&E2c[lrow][lkg * 8];
        const u32x4 aS = *(const u32x4*)&E2s[lrow][lkg * 8];
#pragma unroll
        for (int t = 0; t < 2; ++t) {
            const int dcol = dbase + t * 16 + lrow;
            const size_t ro = ((size_t)b * ND + dcol) * SPAD + k0 + lkg * 8;
            const u32x4 bR = *(const u32x4*)&wsb[FR_OFF + ro];
            const u32x4 bI = *(const u32x4*)&wsb[FI_OFF + ro];
            mfma16(accA[t], aC, bR);
            mfma16(accB[t], aS, bI);
        }
    }

#pragma unroll
    for (int t = 0; t < 2; ++t) {
#pragma unroll
        for (int r = 0; r < 4; ++r) {
            const int trow = tbase + lkg * 4 + r;
            if (trow >= NS) continue;
            const int dcol = dbase + t * 16 + lrow;
            const float vA = accA[t][r], vB = accB[t][r];
            out[((size_t)b * SL + trow) * ND + dcol] = vA - vB;
            if (trow > 0 && 2 * trow != l)
                out[((size_t)b * SL + (l - trow)) * ND + dcol] = vA + vB;
        }
    }
}

extern "C" void kernel_launch(void* const* d_in, const int* in_sizes, int n_in,
                              void* d_out, int out_size, void* d_ws, size_t ws_size,
                              hipStream_t stream) {
    const float* x = (const float*)d_in[0];
    const float* y = (const float*)d_in[1];
    const float* z = (const float*)d_in[2];
    const int* len_x = (const int*)d_in[3];
    const int* len_y = (const int*)d_in[4];
    const int* len_z = (const int*)d_in[5];
    float* wsf = (float*)d_ws;
    unsigned short* wsb = (unsigned short*)d_ws;
    float* out = (float*)d_out;

    k_front<<<928, 256, 0, stream>>>(x, y, z, len_x, wsf, wsb, out);

    k_mlp<<<32, 256, 0, stream>>>(wsf, len_y, len_z,
        (const float*)d_in[6],  (const float*)d_in[7],  (const float*)d_in[8],  (const float*)d_in[9],
        (const float*)d_in[10], (const float*)d_in[11], (const float*)d_in[12], (const float*)d_in[13],
        (const float*)d_in[14], (const float*)d_in[15], (const float*)d_in[16], (const float*)d_in[17],
        (const float*)d_in[18], (const float*)d_in[19], (const float*)d_in[20], (const float*)d_in[21]);

    k_fwd<<<dim3(33, NB), 256, 0, stream>>>(len_x, wsf, wsb);

    k_inv<<<dim3(33, NB), 256, 0, stream>>>(len_x, wsb, out);
}